// Round 4
// baseline (268.126 us; speedup 1.0000x reference)
//
#include <hip/hip_runtime.h>
#include <hip/hip_bf16.h>
#include <math.h>

#define B_  16
#define N_  16
#define T_  48
#define C_  512
#define H_  8
#define HD_ 64
#define L_  768
#define BL_ 12288

typedef __attribute__((ext_vector_type(8))) short b16x8;
typedef __attribute__((ext_vector_type(4))) short b16x4;
typedef __attribute__((ext_vector_type(4))) float f32x4;

__device__ __forceinline__ short f2b(float f) {
  __hip_bfloat16 h = __float2bfloat16(f);
  return *reinterpret_cast<short*>(&h);
}

// ---------------------------------------------------------------------------
// cast x (fp32) -> bf16
// ---------------------------------------------------------------------------
__global__ __launch_bounds__(256) void cast_x_kernel(
    const float* __restrict__ x, short* __restrict__ xb, int n8)
{
  int i = blockIdx.x * 256 + threadIdx.x;
  if (i < n8) {
    const float4* src = (const float4*)(x + (size_t)i * 8);
    float4 a = src[0], b = src[1];
    short tmp[8] = {f2b(a.x), f2b(a.y), f2b(a.z), f2b(a.w),
                    f2b(b.x), f2b(b.y), f2b(b.z), f2b(b.w)};
    *(b16x8*)(xb + (size_t)i * 8) = *(b16x8*)tmp;
  }
}

// ---------------------------------------------------------------------------
// cast + transpose weights: WT[mat][n][k] = W[k][n], mat: 0=Wq 1=Wk 2=Wv 3=Wo
// ---------------------------------------------------------------------------
__global__ __launch_bounds__(256) void cast_w_kernel(
    const float* __restrict__ Wq, const float* __restrict__ Wk,
    const float* __restrict__ Wv, const float* __restrict__ Wo,
    short* __restrict__ WT)
{
  __shared__ float tile[32][33];
  int mat = blockIdx.z;
  const float* W = (mat == 0) ? Wq : (mat == 1) ? Wk : (mat == 2) ? Wv : Wo;
  int k0 = blockIdx.x * 32, n0 = blockIdx.y * 32;
  int tx = threadIdx.x, ty = threadIdx.y;     // 32 x 8
  for (int i = ty; i < 32; i += 8) tile[i][tx] = W[(size_t)(k0 + i) * 512 + n0 + tx];
  __syncthreads();
  short* dst = WT + (size_t)mat * 512 * 512;
  for (int i = ty; i < 32; i += 8)
    dst[(size_t)(n0 + i) * 512 + k0 + tx] = f2b(tile[tx][i]);
}

// ---------------------------------------------------------------------------
// QKV: xb(12288x512,bf16) @ WT[mat] -> q,k in [b][h][l][d]; v DIRECTLY as
// vT [b][h][d][l] (4 acc rows are l-contiguous -> one 8B store). q scaled.
// ---------------------------------------------------------------------------
__global__ __launch_bounds__(256) void qkv_kernel(
    const short* __restrict__ xb, const short* __restrict__ WT,
    short* __restrict__ q, short* __restrict__ k, short* __restrict__ vT)
{
  __shared__ short As[128][32];
  __shared__ short Bs[128][32];
  int tid = threadIdx.x;
  int w = tid >> 6, lane = tid & 63, n16 = lane & 15, quad = lane >> 4;
  int bm = blockIdx.x, bn = blockIdx.y;
  int mat = bn >> 2;
  int ncol0 = (bn & 3) * 128;
  int row0 = bm * 128;
  const short* Wt = WT + (size_t)mat * 262144;
  float scale = (mat == 0) ? 0.125f : 1.0f;

  f32x4 zero4 = {0.f, 0.f, 0.f, 0.f};
  f32x4 acc[4][4];
  #pragma unroll
  for (int mt = 0; mt < 4; ++mt)
    #pragma unroll
    for (int nt = 0; nt < 4; ++nt) acc[mt][nt] = zero4;

  int srow = tid >> 1, sch = (tid & 1) * 16;
  const short* ga = xb + (size_t)(row0 + srow) * 512 + sch;
  const short* gb = Wt + (size_t)(ncol0 + srow) * 512 + sch;
  int wm = (w >> 1) * 64, wn = (w & 1) * 64;

  for (int kt = 0; kt < 16; ++kt) {
    b16x8 a0 = *(const b16x8*)(ga);
    b16x8 a1 = *(const b16x8*)(ga + 8);
    b16x8 b0 = *(const b16x8*)(gb);
    b16x8 b1 = *(const b16x8*)(gb + 8);
    ga += 32; gb += 32;
    __syncthreads();
    *(b16x8*)&As[srow][sch]     = a0;
    *(b16x8*)&As[srow][sch + 8] = a1;
    *(b16x8*)&Bs[srow][sch]     = b0;
    *(b16x8*)&Bs[srow][sch + 8] = b1;
    __syncthreads();
    b16x8 af[4], bf[4];
    #pragma unroll
    for (int mt = 0; mt < 4; ++mt) af[mt] = *(const b16x8*)&As[wm + mt * 16 + n16][quad * 8];
    #pragma unroll
    for (int nt = 0; nt < 4; ++nt) bf[nt] = *(const b16x8*)&Bs[wn + nt * 16 + n16][quad * 8];
    #pragma unroll
    for (int mt = 0; mt < 4; ++mt)
      #pragma unroll
      for (int nt = 0; nt < 4; ++nt)
        acc[mt][nt] = __builtin_amdgcn_mfma_f32_16x16x32_bf16(af[mt], bf[nt], acc[mt][nt], 0, 0, 0);
  }

  if (mat == 2) {
    // v transposed: vT[((bb*8+hh)*64 + d)*768 + l], 4 rows pack to one store
    #pragma unroll
    for (int mt = 0; mt < 4; ++mt) {
      int rowb = row0 + wm + mt * 16 + quad * 4;
      int bb = rowb / 768;
      int l  = rowb - bb * 768;
      #pragma unroll
      for (int nt = 0; nt < 4; ++nt) {
        int colg = ncol0 + wn + nt * 16 + n16;
        int hh = colg >> 6, d = colg & 63;
        short tmp[4];
        #pragma unroll
        for (int r = 0; r < 4; ++r) tmp[r] = f2b(acc[mt][nt][r]);
        *(b16x4*)(vT + ((size_t)(bb * 8 + hh) * 64 + d) * 768 + l) = *(b16x4*)tmp;
      }
    }
  } else {
    short* dst = (mat == 0) ? q : k;
    #pragma unroll
    for (int mt = 0; mt < 4; ++mt) {
      int rowb = row0 + wm + mt * 16 + quad * 4;
      #pragma unroll
      for (int nt = 0; nt < 4; ++nt) {
        int colg = ncol0 + wn + nt * 16 + n16;
        int hh = colg >> 6, d = colg & 63;
        #pragma unroll
        for (int r = 0; r < 4; ++r) {
          int rowg = rowb + r;
          int bb = rowg / 768;
          int l = rowg - bb * 768;
          dst[((size_t)(bb * 8 + hh) * 768 + l) * 64 + d] = f2b(acc[mt][nt][r] * scale);
        }
      }
    }
  }
}

// ---------------------------------------------------------------------------
// Flash attention, MFMA, no-max softmax, fully wave-independent.
// One wave = one (b,h,qn,w) 16-row time band; 2 waves per 128-thr block.
// No barriers at all; biases in registers; P round-trip wave-private LDS.
// ---------------------------------------------------------------------------
__global__ __launch_bounds__(128) void attn_kernel(
    const short* __restrict__ q, const short* __restrict__ k,
    const short* __restrict__ vT,
    const float* __restrict__ relT, const float* __restrict__ relP,
    short* __restrict__ yatt)
{
  __shared__ short P[2][16][72];     // per-wave band; pad cols stay zero

  int tid = threadIdx.x;
  int wv = tid >> 6, lane = tid & 63, n16 = lane & 15, quad = lane >> 4;
  int id = blockIdx.x * 2 + wv;
  int h = id & 7;                    // XCD-locality: head in low bits
  int t = id >> 3;
  int w = t % 3; t = t / 3;          // q time band (rows 16w..16w+15)
  int qn = t & 15;
  int b  = t >> 4;

  { // zero this wave's P (pad cols must be 0 for padded-K PV MFMAs)
    int* pi = (int*)&P[wv][0][0];    // 16*36 = 576 ints
    #pragma unroll
    for (int i = 0; i < 9; ++i) pi[lane + 64 * i] = 0;
  }

  // kn-invariant time bias, in registers
  float btv[3][4];
  #pragma unroll
  for (int nt = 0; nt < 3; ++nt)
    #pragma unroll
    for (int r = 0; r < 4; ++r) {
      int idx = nt * 16 + n16 - w * 16 - quad * 4 - r + 47;
      btv[nt][r] = (nt <= w) ? relT[idx * 8 + h] : 0.f;
    }
  // particle bias per kn (block-uniform loads)
  float bpv[16];
  #pragma unroll
  for (int kn = 0; kn < 16; ++kn)
    bpv[kn] = relP[(kn - qn + 15) * 8 + h];

  const short* qptr = q + ((size_t)(b * 8 + h) * 768 + qn * 48 + w * 16 + n16) * 64 + quad * 8;
  b16x8 qf0 = *(const b16x8*)qptr;
  b16x8 qf1 = *(const b16x8*)(qptr + 32);
  const short* kbase = k + (size_t)(b * 8 + h) * 768 * 64;
  const short* vbase = vT + (size_t)(b * 8 + h) * 64 * 768;

  f32x4 zero4 = {0.f, 0.f, 0.f, 0.f};
  f32x4 o[4];
  float psum[4] = {0.f, 0.f, 0.f, 0.f};
  #pragma unroll
  for (int nt = 0; nt < 4; ++nt) o[nt] = zero4;

  for (int kn = 0; kn < 16; ++kn) {
    // S = Q K^T, sub-tiles nt <= w only (others fully causal-masked)
    f32x4 s[3];
    #pragma unroll
    for (int nt = 0; nt < 3; ++nt) {
      if (nt > w) continue;                       // wave-uniform
      const short* kp = kbase + (size_t)(kn * 48 + nt * 16 + n16) * 64 + quad * 8;
      b16x8 kf0 = *(const b16x8*)kp;
      b16x8 kf1 = *(const b16x8*)(kp + 32);
      f32x4 z = zero4;
      z = __builtin_amdgcn_mfma_f32_16x16x32_bf16(qf0, kf0, z, 0, 0, 0);
      z = __builtin_amdgcn_mfma_f32_16x16x32_bf16(qf1, kf1, z, 0, 0, 0);
      s[nt] = z;
    }

    // P = exp(S + bias); no max-subtraction (logits bounded)
    #pragma unroll
    for (int nt = 0; nt < 3; ++nt) {
      if (nt > w) continue;                       // wave-uniform
      #pragma unroll
      for (int r = 0; r < 4; ++r) {
        float p = __expf(s[nt][r] + btv[nt][r] + bpv[kn]);
        if (nt == w && n16 > quad * 4 + r) p = 0.f;   // diagonal causal mask
        psum[r] += p;
        P[wv][quad * 4 + r][nt * 16 + n16] = f2b(p);
      }
    }

    // O += P V  (A-frag from wave-private LDS; B-frag direct from vT via L2)
    b16x8 pf0 = *(const b16x8*)&P[wv][n16][quad * 8];
    b16x8 pf1;
    if (w == 2) pf1 = *(const b16x8*)&P[wv][n16][quad * 8 + 32];
    #pragma unroll
    for (int nt = 0; nt < 4; ++nt) {
      const short* vp = vbase + (size_t)(nt * 16 + n16) * 768 + kn * 48 + quad * 8;
      b16x8 vf0 = *(const b16x8*)vp;
      o[nt] = __builtin_amdgcn_mfma_f32_16x16x32_bf16(pf0, vf0, o[nt], 0, 0, 0);
      if (w == 2) {                               // kt in [32,64) zero for w<2
        b16x8 vf1 = *(const b16x8*)(vp + 32);
        o[nt] = __builtin_amdgcn_mfma_f32_16x16x32_bf16(pf1, vf1, o[nt], 0, 0, 0);
      }
    }
  }

  // row-sum reduce across the 16 lanes holding each row, then write
  #pragma unroll
  for (int r = 0; r < 4; ++r) {
    float s = psum[r];
    s += __shfl_xor(s, 1); s += __shfl_xor(s, 2);
    s += __shfl_xor(s, 4); s += __shfl_xor(s, 8);
    psum[r] = 1.0f / s;
  }
  size_t orow = (size_t)b * 768 + qn * 48 + w * 16 + quad * 4;
  #pragma unroll
  for (int nt = 0; nt < 4; ++nt) {
    int c = h * 64 + nt * 16 + n16;
    #pragma unroll
    for (int r = 0; r < 4; ++r)
      yatt[(orow + r) * 512 + c] = f2b(o[nt][r] * psum[r]);
  }
}

// ---------------------------------------------------------------------------
// proj: yatt(12288x512,bf16) @ WoT -> out fp32
// ---------------------------------------------------------------------------
__global__ __launch_bounds__(256) void proj_kernel(
    const short* __restrict__ yatt, const short* __restrict__ WT,
    float* __restrict__ out)
{
  __shared__ short As[128][32];
  __shared__ short Bs[128][32];
  int tid = threadIdx.x;
  int w = tid >> 6, lane = tid & 63, n16 = lane & 15, quad = lane >> 4;
  int row0 = blockIdx.x * 128;
  int ncol0 = blockIdx.y * 128;
  const short* Wt = WT + (size_t)3 * 262144;

  f32x4 zero4 = {0.f, 0.f, 0.f, 0.f};
  f32x4 acc[4][4];
  #pragma unroll
  for (int mt = 0; mt < 4; ++mt)
    #pragma unroll
    for (int nt = 0; nt < 4; ++nt) acc[mt][nt] = zero4;

  int srow = tid >> 1, sch = (tid & 1) * 16;
  const short* ga = yatt + (size_t)(row0 + srow) * 512 + sch;
  const short* gb = Wt + (size_t)(ncol0 + srow) * 512 + sch;
  int wm = (w >> 1) * 64, wn = (w & 1) * 64;

  for (int kt = 0; kt < 16; ++kt) {
    b16x8 a0 = *(const b16x8*)(ga);
    b16x8 a1 = *(const b16x8*)(ga + 8);
    b16x8 b0 = *(const b16x8*)(gb);
    b16x8 b1 = *(const b16x8*)(gb + 8);
    ga += 32; gb += 32;
    __syncthreads();
    *(b16x8*)&As[srow][sch]     = a0;
    *(b16x8*)&As[srow][sch + 8] = a1;
    *(b16x8*)&Bs[srow][sch]     = b0;
    *(b16x8*)&Bs[srow][sch + 8] = b1;
    __syncthreads();
    b16x8 af[4], bf[4];
    #pragma unroll
    for (int mt = 0; mt < 4; ++mt) af[mt] = *(const b16x8*)&As[wm + mt * 16 + n16][quad * 8];
    #pragma unroll
    for (int nt = 0; nt < 4; ++nt) bf[nt] = *(const b16x8*)&Bs[wn + nt * 16 + n16][quad * 8];
    #pragma unroll
    for (int mt = 0; mt < 4; ++mt)
      #pragma unroll
      for (int nt = 0; nt < 4; ++nt)
        acc[mt][nt] = __builtin_amdgcn_mfma_f32_16x16x32_bf16(af[mt], bf[nt], acc[mt][nt], 0, 0, 0);
  }

  #pragma unroll
  for (int mt = 0; mt < 4; ++mt) {
    int rowb = row0 + wm + mt * 16 + quad * 4;
    #pragma unroll
    for (int nt = 0; nt < 4; ++nt) {
      int colg = ncol0 + wn + nt * 16 + n16;
      #pragma unroll
      for (int r = 0; r < 4; ++r)
        out[(size_t)(rowb + r) * 512 + colg] = acc[mt][nt][r];
    }
  }
}

// ---------------------------------------------------------------------------
extern "C" void kernel_launch(void* const* d_in, const int* in_sizes, int n_in,
                              void* d_out, int out_size, void* d_ws, size_t ws_size,
                              hipStream_t stream) {
  const float* x    = (const float*)d_in[0];
  const float* Wq   = (const float*)d_in[1];
  const float* Wk   = (const float*)d_in[2];
  const float* Wv   = (const float*)d_in[3];
  const float* Wo   = (const float*)d_in[4];
  const float* relT = (const float*)d_in[5];
  const float* relP = (const float*)d_in[6];

  char* wsb = (char*)d_ws;
  const size_t SZ = (size_t)BL_ * C_ * 2;
  short* xb  = (short*)(wsb);
  short* WT  = (short*)(wsb + SZ);
  short* qb  = (short*)(wsb + SZ + 2097152);
  short* kb  = (short*)(wsb + 2 * SZ + 2097152);
  short* vTb = (short*)(wsb + 3 * SZ + 2097152);
  short* yat = (short*)(wsb + 4 * SZ + 2097152 + 4096);  // slack: attn vf1 pad-read

  cast_x_kernel<<<dim3(3072), dim3(256), 0, stream>>>(x, xb, BL_ * C_ / 8);
  cast_w_kernel<<<dim3(16, 16, 4), dim3(32, 8), 0, stream>>>(Wq, Wk, Wv, Wo, WT);
  qkv_kernel<<<dim3(96, 12), dim3(256), 0, stream>>>(xb, WT, qb, kb, vTb);
  attn_kernel<<<dim3(3072), dim3(128), 0, stream>>>(qb, kb, vTb, relT, relP, yat);
  proj_kernel<<<dim3(96, 4), dim3(256), 0, stream>>>(yat, WT, (float*)d_out);
}

// Round 5
// 246.880 us; speedup vs baseline: 1.0861x; 1.0861x over previous
//
#include <hip/hip_runtime.h>
#include <hip/hip_bf16.h>
#include <math.h>

#define B_  16
#define N_  16
#define T_  48
#define C_  512
#define H_  8
#define HD_ 64
#define L_  768
#define BL_ 12288

typedef __attribute__((ext_vector_type(8))) short b16x8;
typedef __attribute__((ext_vector_type(4))) float f32x4;

__device__ __forceinline__ short f2b(float f) {
  __hip_bfloat16 h = __float2bfloat16(f);
  return *reinterpret_cast<short*>(&h);
}

// ---------------------------------------------------------------------------
// cast x (fp32) -> bf16
// ---------------------------------------------------------------------------
__global__ __launch_bounds__(256) void cast_x_kernel(
    const float* __restrict__ x, short* __restrict__ xb, int n8)
{
  int i = blockIdx.x * 256 + threadIdx.x;
  if (i < n8) {
    const float4* src = (const float4*)(x + (size_t)i * 8);
    float4 a = src[0], b = src[1];
    short tmp[8] = {f2b(a.x), f2b(a.y), f2b(a.z), f2b(a.w),
                    f2b(b.x), f2b(b.y), f2b(b.z), f2b(b.w)};
    *(b16x8*)(xb + (size_t)i * 8) = *(b16x8*)tmp;
  }
}

// ---------------------------------------------------------------------------
// cast + transpose weights: WT[mat][n][k] = W[k][n], mat: 0=Wq 1=Wk 2=Wv 3=Wo
// ---------------------------------------------------------------------------
__global__ __launch_bounds__(256) void cast_w_kernel(
    const float* __restrict__ Wq, const float* __restrict__ Wk,
    const float* __restrict__ Wv, const float* __restrict__ Wo,
    short* __restrict__ WT)
{
  __shared__ float tile[32][33];
  int mat = blockIdx.z;
  const float* W = (mat == 0) ? Wq : (mat == 1) ? Wk : (mat == 2) ? Wv : Wo;
  int k0 = blockIdx.x * 32, n0 = blockIdx.y * 32;
  int tx = threadIdx.x, ty = threadIdx.y;     // 32 x 8
  for (int i = ty; i < 32; i += 8) tile[i][tx] = W[(size_t)(k0 + i) * 512 + n0 + tx];
  __syncthreads();
  short* dst = WT + (size_t)mat * 512 * 512;
  for (int i = ty; i < 32; i += 8)
    dst[(size_t)(n0 + i) * 512 + k0 + tx] = f2b(tile[tx][i]);
}

// ---------------------------------------------------------------------------
// QKV GEMM. Outputs in time-major attention layouts:
//   q2,k2: [b][h][t][n][d]   (16 particles of one timestep contiguous)
//   vT2  : [b][h][d][kt][kn] (PV K-dim kt*16+kn contiguous)
// q scaled by 1/8.
// ---------------------------------------------------------------------------
__global__ __launch_bounds__(256) void qkv_kernel(
    const short* __restrict__ xb, const short* __restrict__ WT,
    short* __restrict__ q2, short* __restrict__ k2, short* __restrict__ vT2)
{
  __shared__ short As[128][32];
  __shared__ short Bs[128][32];
  int tid = threadIdx.x;
  int w = tid >> 6, lane = tid & 63, n16 = lane & 15, quad = lane >> 4;
  int bm = blockIdx.x, bn = blockIdx.y;
  int mat = bn >> 2;
  int ncol0 = (bn & 3) * 128;
  int row0 = bm * 128;
  const short* Wt = WT + (size_t)mat * 262144;
  float scale = (mat == 0) ? 0.125f : 1.0f;

  f32x4 zero4 = {0.f, 0.f, 0.f, 0.f};
  f32x4 acc[4][4];
  #pragma unroll
  for (int mt = 0; mt < 4; ++mt)
    #pragma unroll
    for (int nt = 0; nt < 4; ++nt) acc[mt][nt] = zero4;

  int srow = tid >> 1, sch = (tid & 1) * 16;
  const short* ga = xb + (size_t)(row0 + srow) * 512 + sch;
  const short* gb = Wt + (size_t)(ncol0 + srow) * 512 + sch;
  int wm = (w >> 1) * 64, wn = (w & 1) * 64;

  for (int kt = 0; kt < 16; ++kt) {
    b16x8 a0 = *(const b16x8*)(ga);
    b16x8 a1 = *(const b16x8*)(ga + 8);
    b16x8 b0 = *(const b16x8*)(gb);
    b16x8 b1 = *(const b16x8*)(gb + 8);
    ga += 32; gb += 32;
    __syncthreads();
    *(b16x8*)&As[srow][sch]     = a0;
    *(b16x8*)&As[srow][sch + 8] = a1;
    *(b16x8*)&Bs[srow][sch]     = b0;
    *(b16x8*)&Bs[srow][sch + 8] = b1;
    __syncthreads();
    b16x8 af[4], bf[4];
    #pragma unroll
    for (int mt = 0; mt < 4; ++mt) af[mt] = *(const b16x8*)&As[wm + mt * 16 + n16][quad * 8];
    #pragma unroll
    for (int nt = 0; nt < 4; ++nt) bf[nt] = *(const b16x8*)&Bs[wn + nt * 16 + n16][quad * 8];
    #pragma unroll
    for (int mt = 0; mt < 4; ++mt)
      #pragma unroll
      for (int nt = 0; nt < 4; ++nt)
        acc[mt][nt] = __builtin_amdgcn_mfma_f32_16x16x32_bf16(af[mt], bf[nt], acc[mt][nt], 0, 0, 0);
  }

  #pragma unroll
  for (int mt = 0; mt < 4; ++mt) {
    int rowb = row0 + wm + mt * 16 + quad * 4;   // global row, mult of 4
    int bb = rowb / 768;
    int l0 = rowb - bb * 768;
    int pn = l0 / 48;                             // particle
    int pt = l0 - pn * 48;                        // time (mult of 4, pt+3 < 48)
    #pragma unroll
    for (int nt = 0; nt < 4; ++nt) {
      int colg = ncol0 + wn + nt * 16 + n16;
      int hh = colg >> 6, d = colg & 63;
      if (mat == 2) {
        #pragma unroll
        for (int r = 0; r < 4; ++r)
          vT2[(((size_t)(bb * 8 + hh) * 64 + d) * 48 + pt + r) * 16 + pn] = f2b(acc[mt][nt][r]);
      } else {
        short* dst = (mat == 0) ? q2 : k2;
        #pragma unroll
        for (int r = 0; r < 4; ++r)
          dst[(((size_t)(bb * 8 + hh) * 48 + pt + r) * 16 + pn) * 64 + d] = f2b(acc[mt][nt][r] * scale);
      }
    }
  }
}

// ---------------------------------------------------------------------------
// Attention, time-major tiling. Wave = (b,h, qt-pair {qt, 47-qt}).
// Tile (qt,kt) is 16 particles x 16 particles, included iff kt<=qt (no
// partial masks). bias_t tile-constant, bias_p lane-constant. 25 kt-pairs
// per wave (perfectly balanced). No barriers; P round-trip wave-private LDS.
// ---------------------------------------------------------------------------
__global__ __launch_bounds__(128) void attn_kernel(
    const short* __restrict__ q2, const short* __restrict__ k2,
    const short* __restrict__ vT2,
    const float* __restrict__ relT, const float* __restrict__ relP,
    short* __restrict__ yatt)
{
  __shared__ short P[2][2][2][16][40];   // [wave][band][parity][qn][k2], pad 40
  __shared__ float btL[2][96];

  int tid = threadIdx.x;
  int wv = tid >> 6, lane = tid & 63, n16 = lane & 15, quad = lane >> 4;
  int blk = blockIdx.x;
  int h = blk & 7;                  // XCD-locality
  int g = blk >> 3;                 // 0..191
  int pg = g % 12, b = g / 12;
  int pair = pg * 2 + wv;           // 0..23
  int qtA = pair, qtB = 47 - pair;
  int nA = (qtA + 2) >> 1, nB = (qtB + 2) >> 1;   // nA + nB == 25

  // per-wave copy of this head's time-bias row (wave-private, no barrier)
  btL[wv][lane] = relT[(lane < 95 ? lane : 94) * 8 + h];
  if (lane < 31) btL[wv][64 + lane] = relT[(64 + lane) * 8 + h];

  float bp4[4];
  #pragma unroll
  for (int r = 0; r < 4; ++r)
    bp4[r] = relP[(n16 - quad * 4 - r + 15) * 8 + h];   // (kn - qn + 15)

  size_t bh = (size_t)(b * 8 + h);
  const short* qb = q2 + bh * 49152;
  const short* kb = k2 + bh * 49152;
  const short* vb = vT2 + bh * 49152;

  b16x8 qA0 = *(const b16x8*)(qb + (qtA * 16 + n16) * 64 + quad * 8);
  b16x8 qA1 = *(const b16x8*)(qb + (qtA * 16 + n16) * 64 + quad * 8 + 32);
  b16x8 qB0 = *(const b16x8*)(qb + (qtB * 16 + n16) * 64 + quad * 8);
  b16x8 qB1 = *(const b16x8*)(qb + (qtB * 16 + n16) * 64 + quad * 8 + 32);

  f32x4 zero4 = {0.f, 0.f, 0.f, 0.f};
  f32x4 oA[4], oB[4];
  float psA[4] = {0, 0, 0, 0}, psB[4] = {0, 0, 0, 0};
  #pragma unroll
  for (int nt = 0; nt < 4; ++nt) { oA[nt] = zero4; oB[nt] = zero4; }

  // prefetch kt2 = 0
  b16x8 kf[4], vf[4];
  #pragma unroll
  for (int t = 0; t < 2; ++t) {
    kf[2 * t]     = *(const b16x8*)(kb + (t * 16 + n16) * 64 + quad * 8);
    kf[2 * t + 1] = *(const b16x8*)(kb + (t * 16 + n16) * 64 + quad * 8 + 32);
  }
  #pragma unroll
  for (int nt = 0; nt < 4; ++nt)
    vf[nt] = *(const b16x8*)(vb + (nt * 16 + n16) * 768 + quad * 8);

  for (int kt2 = 0; kt2 < nB; ++kt2) {
    b16x8 nkf[4], nvf[4];
    if (kt2 + 1 < nB) {               // wave-uniform prefetch
      int kt0n = (kt2 + 1) * 2;
      #pragma unroll
      for (int t = 0; t < 2; ++t) {
        nkf[2 * t]     = *(const b16x8*)(kb + ((kt0n + t) * 16 + n16) * 64 + quad * 8);
        nkf[2 * t + 1] = *(const b16x8*)(kb + ((kt0n + t) * 16 + n16) * 64 + quad * 8 + 32);
      }
      #pragma unroll
      for (int nt = 0; nt < 4; ++nt)
        nvf[nt] = *(const b16x8*)(vb + (nt * 16 + n16) * 768 + (kt2 + 1) * 32 + quad * 8);
    }
    int par = kt2 & 1;
    int kt0 = kt2 * 2;

    // ---- band B (always active) ----
    {
      short (*Pb)[40] = P[wv][1][par];
      #pragma unroll
      for (int ktl = 0; ktl < 2; ++ktl) {
        f32x4 s = zero4;
        s = __builtin_amdgcn_mfma_f32_16x16x32_bf16(qB0, kf[2 * ktl], s, 0, 0, 0);
        s = __builtin_amdgcn_mfma_f32_16x16x32_bf16(qB1, kf[2 * ktl + 1], s, 0, 0, 0);
        int kt = kt0 + ktl;
        float btv = (kt <= qtB) ? btL[wv][kt - qtB + 47] : -1e30f;
        #pragma unroll
        for (int r = 0; r < 4; ++r) {
          float p = __expf(s[r] + btv + bp4[r]);
          psB[r] += p;
          Pb[quad * 4 + r][ktl * 16 + n16] = f2b(p);
        }
      }
      b16x8 pf = *(const b16x8*)&Pb[n16][quad * 8];
      #pragma unroll
      for (int nt = 0; nt < 4; ++nt)
        oB[nt] = __builtin_amdgcn_mfma_f32_16x16x32_bf16(pf, vf[nt], oB[nt], 0, 0, 0);
    }

    // ---- band A ----
    if (kt2 < nA) {                   // wave-uniform
      short (*Pb)[40] = P[wv][0][par];
      #pragma unroll
      for (int ktl = 0; ktl < 2; ++ktl) {
        f32x4 s = zero4;
        s = __builtin_amdgcn_mfma_f32_16x16x32_bf16(qA0, kf[2 * ktl], s, 0, 0, 0);
        s = __builtin_amdgcn_mfma_f32_16x16x32_bf16(qA1, kf[2 * ktl + 1], s, 0, 0, 0);
        int kt = kt0 + ktl;
        float btv = (kt <= qtA) ? btL[wv][kt - qtA + 47] : -1e30f;
        #pragma unroll
        for (int r = 0; r < 4; ++r) {
          float p = __expf(s[r] + btv + bp4[r]);
          psA[r] += p;
          Pb[quad * 4 + r][ktl * 16 + n16] = f2b(p);
        }
      }
      b16x8 pf = *(const b16x8*)&Pb[n16][quad * 8];
      #pragma unroll
      for (int nt = 0; nt < 4; ++nt)
        oA[nt] = __builtin_amdgcn_mfma_f32_16x16x32_bf16(pf, vf[nt], oA[nt], 0, 0, 0);
    }

    #pragma unroll
    for (int i = 0; i < 4; ++i) { kf[i] = nkf[i]; vf[i] = nvf[i]; }
  }

  // normalize: psum reduce over kn lanes (n16 bits of lane id)
  #pragma unroll
  for (int r = 0; r < 4; ++r) {
    float sA = psA[r], sB = psB[r];
    sA += __shfl_xor(sA, 1); sA += __shfl_xor(sA, 2);
    sA += __shfl_xor(sA, 4); sA += __shfl_xor(sA, 8);
    sB += __shfl_xor(sB, 1); sB += __shfl_xor(sB, 2);
    sB += __shfl_xor(sB, 4); sB += __shfl_xor(sB, 8);
    psA[r] = 1.0f / sA; psB[r] = 1.0f / sB;
  }
  // store: row l = qn*48 + qt, col = h*64 + d
  #pragma unroll
  for (int nt = 0; nt < 4; ++nt) {
    int c = h * 64 + nt * 16 + n16;
    #pragma unroll
    for (int r = 0; r < 4; ++r) {
      int qn = quad * 4 + r;
      yatt[((size_t)b * 768 + qn * 48 + qtA) * 512 + c] = f2b(oA[nt][r] * psA[r]);
      yatt[((size_t)b * 768 + qn * 48 + qtB) * 512 + c] = f2b(oB[nt][r] * psB[r]);
    }
  }
}

// ---------------------------------------------------------------------------
// proj: yatt(12288x512,bf16) @ WoT -> out fp32
// ---------------------------------------------------------------------------
__global__ __launch_bounds__(256) void proj_kernel(
    const short* __restrict__ yatt, const short* __restrict__ WT,
    float* __restrict__ out)
{
  __shared__ short As[128][32];
  __shared__ short Bs[128][32];
  int tid = threadIdx.x;
  int w = tid >> 6, lane = tid & 63, n16 = lane & 15, quad = lane >> 4;
  int row0 = blockIdx.x * 128;
  int ncol0 = blockIdx.y * 128;
  const short* Wt = WT + (size_t)3 * 262144;

  f32x4 zero4 = {0.f, 0.f, 0.f, 0.f};
  f32x4 acc[4][4];
  #pragma unroll
  for (int mt = 0; mt < 4; ++mt)
    #pragma unroll
    for (int nt = 0; nt < 4; ++nt) acc[mt][nt] = zero4;

  int srow = tid >> 1, sch = (tid & 1) * 16;
  const short* ga = yatt + (size_t)(row0 + srow) * 512 + sch;
  const short* gb = Wt + (size_t)(ncol0 + srow) * 512 + sch;
  int wm = (w >> 1) * 64, wn = (w & 1) * 64;

  for (int kt = 0; kt < 16; ++kt) {
    b16x8 a0 = *(const b16x8*)(ga);
    b16x8 a1 = *(const b16x8*)(ga + 8);
    b16x8 b0 = *(const b16x8*)(gb);
    b16x8 b1 = *(const b16x8*)(gb + 8);
    ga += 32; gb += 32;
    __syncthreads();
    *(b16x8*)&As[srow][sch]     = a0;
    *(b16x8*)&As[srow][sch + 8] = a1;
    *(b16x8*)&Bs[srow][sch]     = b0;
    *(b16x8*)&Bs[srow][sch + 8] = b1;
    __syncthreads();
    b16x8 af[4], bf[4];
    #pragma unroll
    for (int mt = 0; mt < 4; ++mt) af[mt] = *(const b16x8*)&As[wm + mt * 16 + n16][quad * 8];
    #pragma unroll
    for (int nt = 0; nt < 4; ++nt) bf[nt] = *(const b16x8*)&Bs[wn + nt * 16 + n16][quad * 8];
    #pragma unroll
    for (int mt = 0; mt < 4; ++mt)
      #pragma unroll
      for (int nt = 0; nt < 4; ++nt)
        acc[mt][nt] = __builtin_amdgcn_mfma_f32_16x16x32_bf16(af[mt], bf[nt], acc[mt][nt], 0, 0, 0);
  }

  #pragma unroll
  for (int mt = 0; mt < 4; ++mt) {
    int rowb = row0 + wm + mt * 16 + quad * 4;
    #pragma unroll
    for (int nt = 0; nt < 4; ++nt) {
      int colg = ncol0 + wn + nt * 16 + n16;
      #pragma unroll
      for (int r = 0; r < 4; ++r)
        out[(size_t)(rowb + r) * 512 + colg] = acc[mt][nt][r];
    }
  }
}

// ---------------------------------------------------------------------------
extern "C" void kernel_launch(void* const* d_in, const int* in_sizes, int n_in,
                              void* d_out, int out_size, void* d_ws, size_t ws_size,
                              hipStream_t stream) {
  const float* x    = (const float*)d_in[0];
  const float* Wq   = (const float*)d_in[1];
  const float* Wk   = (const float*)d_in[2];
  const float* Wv   = (const float*)d_in[3];
  const float* Wo   = (const float*)d_in[4];
  const float* relT = (const float*)d_in[5];
  const float* relP = (const float*)d_in[6];

  char* wsb = (char*)d_ws;
  const size_t SZ = (size_t)BL_ * C_ * 2;
  short* xb  = (short*)(wsb);
  short* WT  = (short*)(wsb + SZ);
  short* qb  = (short*)(wsb + SZ + 2097152);
  short* kb  = (short*)(wsb + 2 * SZ + 2097152);
  short* vTb = (short*)(wsb + 3 * SZ + 2097152);
  short* yat = (short*)(wsb + 4 * SZ + 2097152 + 4096);

  cast_x_kernel<<<dim3(3072), dim3(256), 0, stream>>>(x, xb, BL_ * C_ / 8);
  cast_w_kernel<<<dim3(16, 16, 4), dim3(32, 8), 0, stream>>>(Wq, Wk, Wv, Wo, WT);
  qkv_kernel<<<dim3(96, 12), dim3(256), 0, stream>>>(xb, WT, qb, kb, vTb);
  attn_kernel<<<dim3(1536), dim3(128), 0, stream>>>(qb, kb, vTb, relT, relP, yat);
  proj_kernel<<<dim3(96, 4), dim3(256), 0, stream>>>(yat, WT, (float*)d_out);
}